// Round 1
// baseline (895.252 us; speedup 1.0000x reference)
//
#include <hip/hip_runtime.h>

#define G 64
#define N 2048
#define E 32768
#define GN (G*N)   // 131072

__device__ __forceinline__ float4 ld4(const float* p) { return *reinterpret_cast<const float4*>(p); }
__device__ __forceinline__ void st4(float* p, float4 v) { *reinterpret_cast<float4*>(p) = v; }

// ---------------- CSR build ----------------
__global__ void k_count(const int* __restrict__ ei, int* __restrict__ cnt) {
    int i = blockIdx.x * 256 + threadIdx.x;
    if (i >= G*E) return;
    int g = i >> 15, e = i & (E-1);
    int dst = ei[(size_t)g*2*E + E + e];
    atomicAdd(&cnt[(g<<11) + dst], 1);
}

__global__ __launch_bounds__(256) void k_scan(const int* __restrict__ cnt,
        int* __restrict__ offs, int* __restrict__ cursor, float* __restrict__ dinv) {
    int g = blockIdx.x, t = threadIdx.x;
    __shared__ int s[256];
    int base = 0;
    for (int c = 0; c < N/256; ++c) {
        int n = c*256 + t;
        int v = cnt[(g<<11) + n];
        s[t] = v; __syncthreads();
        for (int off = 1; off < 256; off <<= 1) {
            int x = (t >= off) ? s[t-off] : 0;
            __syncthreads();
            s[t] += x;
            __syncthreads();
        }
        int excl = base + s[t] - v;
        offs[g*(N+1) + n] = excl;
        cursor[(g<<11) + n] = excl;
        dinv[(g<<11) + n] = rsqrtf((float)(v + 1));   // +1 self-loop
        base += s[255];
        __syncthreads();
    }
    if (t == 0) offs[g*(N+1) + N] = base;
}

__global__ void k_fill(const int* __restrict__ ei, int* __restrict__ cursor, int* __restrict__ adj) {
    int i = blockIdx.x * 256 + threadIdx.x;
    if (i >= G*E) return;
    int g = i >> 15, e = i & (E-1);
    int src = ei[(size_t)g*2*E + e];
    int dst = ei[(size_t)g*2*E + E + e];
    int pos = atomicAdd(&cursor[(g<<11) + dst], 1);
    adj[(size_t)g*E + pos] = src;
}

// ---------------- gather x0 ----------------
__global__ void k_gather(const float* __restrict__ tab, const int* __restrict__ fidx,
                         float* __restrict__ x0) {
    int i = blockIdx.x * 256 + threadIdx.x;   // GN*32 float4s
    int row = i >> 5, j = i & 31;
    int f = fidx[row];
    st4(x0 + (size_t)row*128 + j*4, ld4(tab + (size_t)f*128 + j*4));
}

// ---------------- GEMM: [GN,128] x [128,128] ----------------
// MODE 0: C = relu(A@W + bias)
// MODE 1: C = (A@W) * dinv[row]          (pre-scale for aggregation)
// MODE 2: C = relu((A+A2)@W + bias)
template<int MODE>
__global__ __launch_bounds__(256) void k_gemm(const float* __restrict__ A,
        const float* __restrict__ A2, const float* __restrict__ W,
        const float* __restrict__ bias, const float* __restrict__ dinv,
        float* __restrict__ C) {
    // sA: transposed + XOR-swizzled: A[r][k] at word k*128 + 4*((r>>2) ^ ((k>>2)&7)) + (r&3)
    __shared__ float sA[128*128];
    __shared__ float sW[128*128];   // row-major
    const int t = threadIdx.x;
    const size_t row0 = (size_t)blockIdx.x * 128;

    // stage W (linear, conflict-free)
    #pragma unroll
    for (int i = 0; i < 16; ++i) {
        int idx = (i*256 + t) * 4;
        st4(&sW[idx], ld4(W + idx));
    }
    // stage A tile: 4x4 micro-blocks, register transpose, swizzled b128 writes
    #pragma unroll
    for (int i = 0; i < 4; ++i) {
        int bid = i*256 + t;           // 0..1023
        int kq = bid & 31, rq = bid >> 5;
        const float* ap = A + (row0 + rq*4)*128 + kq*4;
        float4 r0 = ld4(ap), r1 = ld4(ap+128), r2 = ld4(ap+256), r3 = ld4(ap+384);
        if (MODE == 2) {
            const float* ap2 = A2 + (row0 + rq*4)*128 + kq*4;
            float4 q0 = ld4(ap2), q1 = ld4(ap2+128), q2 = ld4(ap2+256), q3 = ld4(ap2+384);
            r0.x+=q0.x; r0.y+=q0.y; r0.z+=q0.z; r0.w+=q0.w;
            r1.x+=q1.x; r1.y+=q1.y; r1.z+=q1.z; r1.w+=q1.w;
            r2.x+=q2.x; r2.y+=q2.y; r2.z+=q2.z; r2.w+=q2.w;
            r3.x+=q3.x; r3.y+=q3.y; r3.z+=q3.z; r3.w+=q3.w;
        }
        float* dst = &sA[(kq*4)*128 + ((rq ^ (kq & 7)) * 4)];
        st4(dst,       make_float4(r0.x, r1.x, r2.x, r3.x));
        st4(dst + 128, make_float4(r0.y, r1.y, r2.y, r3.y));
        st4(dst + 256, make_float4(r0.z, r1.z, r2.z, r3.z));
        st4(dst + 384, make_float4(r0.w, r1.w, r2.w, r3.w));
    }
    __syncthreads();

    const int cb = (t & 15) * 4;   // cols cb..cb+3 and cb+64..cb+67
    const int rb = (t >> 4);       // row blocks rb and rb+16 (rows rb*4.. / rb*4+64..)
    float acc[8][8];
    #pragma unroll
    for (int ii = 0; ii < 8; ++ii)
        #pragma unroll
        for (int jj = 0; jj < 8; ++jj) acc[ii][jj] = 0.f;

    for (int kq = 0; kq < 32; ++kq) {
        const int s = kq & 7;
        const int offA0 = (rb ^ s) * 4;
        const int offA1 = offA0 + 64;
        #pragma unroll
        for (int j = 0; j < 4; ++j) {
            const int k = kq*4 + j;
            const float* base = &sA[k*128];
            float4 a0 = ld4(base + offA0);
            float4 a1 = ld4(base + offA1);
            const float* wb = &sW[k*128];
            float4 w0 = ld4(wb + cb);
            float4 w1 = ld4(wb + cb + 64);
            float av[8] = {a0.x,a0.y,a0.z,a0.w,a1.x,a1.y,a1.z,a1.w};
            float wv[8] = {w0.x,w0.y,w0.z,w0.w,w1.x,w1.y,w1.z,w1.w};
            #pragma unroll
            for (int ii = 0; ii < 8; ++ii)
                #pragma unroll
                for (int jj = 0; jj < 8; ++jj)
                    acc[ii][jj] += av[ii] * wv[jj];
        }
    }

    float4 b0 = make_float4(0,0,0,0), b1 = make_float4(0,0,0,0);
    if (MODE != 1) { b0 = ld4(bias + cb); b1 = ld4(bias + cb + 64); }
    #pragma unroll
    for (int ii = 0; ii < 8; ++ii) {
        size_t r = row0 + rb*4 + (ii & 3) + (ii >> 2)*64;
        float4 v0 = make_float4(acc[ii][0], acc[ii][1], acc[ii][2], acc[ii][3]);
        float4 v1 = make_float4(acc[ii][4], acc[ii][5], acc[ii][6], acc[ii][7]);
        if (MODE == 1) {
            float d = dinv[r];
            v0.x*=d; v0.y*=d; v0.z*=d; v0.w*=d;
            v1.x*=d; v1.y*=d; v1.z*=d; v1.w*=d;
        } else {
            v0.x = fmaxf(v0.x + b0.x, 0.f); v0.y = fmaxf(v0.y + b0.y, 0.f);
            v0.z = fmaxf(v0.z + b0.z, 0.f); v0.w = fmaxf(v0.w + b0.w, 0.f);
            v1.x = fmaxf(v1.x + b1.x, 0.f); v1.y = fmaxf(v1.y + b1.y, 0.f);
            v1.z = fmaxf(v1.z + b1.z, 0.f); v1.w = fmaxf(v1.w + b1.w, 0.f);
        }
        st4(C + r*128 + cb, v0);
        st4(C + r*128 + cb + 64, v1);
    }
}

// ---------------- aggregation (pull via CSR) ----------------
// out[n] = relu(dinv[n] * (sum_{e: dst=n} h'[src] + h'[n]) + bias)   (h' pre-scaled by dinv[src])
__global__ __launch_bounds__(256) void k_agg(const float* __restrict__ h,
        const int* __restrict__ adj, const int* __restrict__ offs,
        const float* __restrict__ dinv, const float* __restrict__ bias,
        float* __restrict__ out) {
    int wid = blockIdx.x * 4 + (threadIdx.x >> 6);   // one wave per node
    int lane = threadIdx.x & 63;
    int g = wid >> 11, n = wid & (N-1);
    const float* hg = h + (size_t)(g << 11) * 128;
    int st = offs[g*(N+1) + n];
    int en = offs[g*(N+1) + n + 1];
    const int* al = adj + (size_t)g*E;
    const int c = lane*2;
    const float* ps = hg + (size_t)n*128 + c;
    float ax = ps[0], ay = ps[1];   // self-loop term
    int e = st;
    for (; e + 4 <= en; e += 4) {
        int s0 = al[e], s1 = al[e+1], s2 = al[e+2], s3 = al[e+3];
        const float* p0 = hg + (size_t)s0*128 + c;
        const float* p1 = hg + (size_t)s1*128 + c;
        const float* p2 = hg + (size_t)s2*128 + c;
        const float* p3 = hg + (size_t)s3*128 + c;
        float x0=p0[0], y0=p0[1], x1=p1[0], y1=p1[1];
        float x2=p2[0], y2=p2[1], x3=p3[0], y3=p3[1];
        ax += (x0 + x1) + (x2 + x3);
        ay += (y0 + y1) + (y2 + y3);
    }
    for (; e < en; ++e) {
        const float* p = hg + (size_t)al[e]*128 + c;
        ax += p[0]; ay += p[1];
    }
    float d = dinv[wid];
    float rx = fmaxf(ax*d + bias[c],   0.f);
    float ry = fmaxf(ay*d + bias[c+1], 0.f);
    out[(size_t)wid*128 + c]     = rx;
    out[(size_t)wid*128 + c + 1] = ry;
}

// ---------------- mean over nodes (partial + atomic) ----------------
__global__ __launch_bounds__(128) void k_mean(const float* __restrict__ y, float* __restrict__ tgt) {
    int g = blockIdx.x >> 3, part = blockIdx.x & 7;
    int c = threadIdx.x;
    float s = 0.f;
    const float* p = y + ((size_t)g*N + part*256)*128 + c;
    for (int n = 0; n < 256; ++n) s += p[(size_t)n*128];
    atomicAdd(&tgt[g*128 + c], s);
}

// ---------------- logits + log_softmax ----------------
__global__ void k_final(const float* __restrict__ tgt, const float* __restrict__ lw,
        const float* __restrict__ lb, float* __restrict__ outp) {
    int g = blockIdx.x * blockDim.x + threadIdx.x;
    if (g >= G) return;
    float l0 = lb[0], l1 = lb[1];
    for (int c = 0; c < 128; ++c) {
        float v = tgt[g*128 + c] * (1.0f/2048.0f);
        l0 += v * lw[c*2];
        l1 += v * lw[c*2 + 1];
    }
    float m = fmaxf(l0, l1);
    float lse = m + logf(expf(l0 - m) + expf(l1 - m));
    outp[g*2]         = l0 - lse;
    outp[g*2 + 1]     = l1 - lse;
    outp[G*2 + g*2]     = l0;
    outp[G*2 + g*2 + 1] = l1;
}

extern "C" void kernel_launch(void* const* d_in, const int* in_sizes, int n_in,
                              void* d_out, int out_size, void* d_ws, size_t ws_size,
                              hipStream_t stream) {
    const float* all_features = (const float*)d_in[0];
    const int*   fidx = (const int*)d_in[1];
    const int*   ei   = (const int*)d_in[2];
    // d_in[3] = action (always 2 in setup -> 3 GCN layers)
    const float* wres = (const float*)d_in[4];
    const float* bres = (const float*)d_in[5];
    const float* gw   = (const float*)d_in[6];
    const float* gb   = (const float*)d_in[7];
    const float* wfc  = (const float*)d_in[8];
    const float* bfc  = (const float*)d_in[9];
    const float* lw   = (const float*)d_in[10];
    const float* lb   = (const float*)d_in[11];
    float* out = (float*)d_out;

    char* ws = (char*)d_ws;
    size_t o = 0;
    auto alloc = [&](size_t bytes) { char* p = ws + o; o += (bytes + 255) & ~(size_t)255; return p; };
    float* X    = (float*)alloc((size_t)GN*128*4);   // node features (x)
    float* Hb   = (float*)alloc((size_t)GN*128*4);   // h' / final y
    float* X1   = (float*)alloc((size_t)GN*128*4);   // residual branch
    int*   adj    = (int*)alloc((size_t)G*E*4);
    int*   cnt    = (int*)alloc((size_t)GN*4);
    int*   offs   = (int*)alloc((size_t)G*(N+1)*4);
    int*   cursor = (int*)alloc((size_t)GN*4);
    float* dinv   = (float*)alloc((size_t)GN*4);
    float* tgt    = (float*)alloc((size_t)G*128*4);

    hipMemsetAsync(cnt, 0, (size_t)GN*4, stream);
    hipMemsetAsync(tgt, 0, (size_t)G*128*4, stream);

    k_count<<<G*E/256, 256, 0, stream>>>(ei, cnt);
    k_scan<<<G, 256, 0, stream>>>(cnt, offs, cursor, dinv);
    k_fill<<<G*E/256, 256, 0, stream>>>(ei, cursor, adj);
    k_gather<<<GN*32/256, 256, 0, stream>>>(all_features, fidx, X);

    // residual: X1 = relu(X @ Wres + bres)
    k_gemm<0><<<GN/128, 256, 0, stream>>>(X, nullptr, wres, bres, nullptr, X1);

    // 3 GCN layers
    for (int l = 0; l < 3; ++l) {
        k_gemm<1><<<GN/128, 256, 0, stream>>>(X, nullptr, gw + (size_t)l*128*128, nullptr, dinv, Hb);
        k_agg<<<GN/4, 256, 0, stream>>>(Hb, adj, offs, dinv, gb + (size_t)l*128, X);
    }

    // fc1: Hb = relu((X + X1) @ Wfc + bfc)
    k_gemm<2><<<GN/128, 256, 0, stream>>>(X, X1, wfc, bfc, nullptr, Hb);

    k_mean<<<G*8, 128, 0, stream>>>(Hb, tgt);
    k_final<<<1, 64, 0, stream>>>(tgt, lw, lb, out);
}

// Round 2
// 570.273 us; speedup vs baseline: 1.5699x; 1.5699x over previous
//
#include <hip/hip_runtime.h>

#define G 64
#define N 2048
#define E 32768
#define GN (G*N)   // 131072

typedef __attribute__((ext_vector_type(8))) short bf16x8;
typedef __attribute__((ext_vector_type(4))) float f32x4;

__device__ __forceinline__ float4 ld4(const float* p) { return *reinterpret_cast<const float4*>(p); }
__device__ __forceinline__ void st4(float* p, float4 v) { *reinterpret_cast<float4*>(p) = v; }
__device__ __forceinline__ unsigned short f2bf(float x) {   // RNE
    unsigned u = __float_as_uint(x);
    u += 0x7FFF + ((u >> 16) & 1);
    return (unsigned short)(u >> 16);
}
__device__ __forceinline__ unsigned pack2(float a, float b) {
    return (unsigned)f2bf(a) | ((unsigned)f2bf(b) << 16);
}
__device__ __forceinline__ float bflo(unsigned u) { return __uint_as_float(u << 16); }
__device__ __forceinline__ float bfhi(unsigned u) { return __uint_as_float(u & 0xFFFF0000u); }
__device__ __forceinline__ float bfs(short s) { return __uint_as_float(((unsigned)(unsigned short)s) << 16); }

// ---------------- CSR build ----------------
__global__ void k_count(const int* __restrict__ ei, int* __restrict__ cnt) {
    int i = blockIdx.x * 256 + threadIdx.x;
    if (i >= G*E) return;
    int g = i >> 15, e = i & (E-1);
    int dst = ei[(size_t)g*2*E + E + e];
    atomicAdd(&cnt[(g<<11) + dst], 1);
}

__global__ __launch_bounds__(256) void k_scan(const int* __restrict__ cnt,
        int* __restrict__ offs, int* __restrict__ cursor, float* __restrict__ dinv) {
    int g = blockIdx.x, t = threadIdx.x;
    __shared__ int s[256];
    int base = 0;
    for (int c = 0; c < N/256; ++c) {
        int n = c*256 + t;
        int v = cnt[(g<<11) + n];
        s[t] = v; __syncthreads();
        for (int off = 1; off < 256; off <<= 1) {
            int x = (t >= off) ? s[t-off] : 0;
            __syncthreads();
            s[t] += x;
            __syncthreads();
        }
        int excl = base + s[t] - v;
        offs[g*(N+1) + n] = excl;
        cursor[(g<<11) + n] = excl;
        dinv[(g<<11) + n] = rsqrtf((float)(v + 1));   // +1 self-loop
        base += s[255];
        __syncthreads();
    }
    if (t == 0) offs[g*(N+1) + N] = base;
}

__global__ void k_fill(const int* __restrict__ ei, int* __restrict__ cursor, int* __restrict__ adj) {
    int i = blockIdx.x * 256 + threadIdx.x;
    if (i >= G*E) return;
    int g = i >> 15, e = i & (E-1);
    int src = ei[(size_t)g*2*E + e];
    int dst = ei[(size_t)g*2*E + E + e];
    int pos = atomicAdd(&cursor[(g<<11) + dst], 1);
    adj[(size_t)g*E + pos] = src;
}

// ---------------- gather x0 (fp32 table -> bf16) ----------------
__global__ void k_gather(const float* __restrict__ tab, const int* __restrict__ fidx,
                         unsigned short* __restrict__ X) {
    int i = blockIdx.x * 256 + threadIdx.x;   // GN*32 threads, 4 cols each
    int row = i >> 5, q = i & 31;
    int f = fidx[row];
    float4 v = ld4(tab + (size_t)f*128 + q*4);
    uint2 p; p.x = pack2(v.x, v.y); p.y = pack2(v.z, v.w);
    *reinterpret_cast<uint2*>(X + ((size_t)row << 7) + q*4) = p;
}

// ---------------- weight prep: fp32 [k][c] -> bf16 Wt[c][k], k-chunk XOR-swizzled ----------------
// chunk q (k=q*8..q*8+7) of col c stored at shorts: m*16384 + c*128 + ((q ^ (c&7))<<3)
__global__ void k_prepw(const float* __restrict__ wres, const float* __restrict__ gw,
                        const float* __restrict__ wfc, unsigned short* __restrict__ Wt) {
    int b = blockIdx.x;                // 40 blocks: 5 matrices x 8
    int m = b >> 3;
    int tid = (b & 7) * 256 + threadIdx.x;   // 0..2047
    const float* src = (m == 0) ? wres : (m < 4 ? gw + (size_t)(m-1)*16384 : wfc);
    int c = tid >> 4, q = tid & 15;
    float v[8];
    #pragma unroll
    for (int j = 0; j < 8; ++j) v[j] = src[(q*8 + j)*128 + c];
    uint4 p;
    p.x = pack2(v[0], v[1]); p.y = pack2(v[2], v[3]);
    p.z = pack2(v[4], v[5]); p.w = pack2(v[6], v[7]);
    *reinterpret_cast<uint4*>(Wt + (size_t)m*16384 + c*128 + ((q ^ (c & 7)) << 3)) = p;
}

// ---------------- MFMA GEMM: [GN,128]bf16 x [128,128] -> [GN,128]bf16 ----------------
// MODE 0: C = relu(A@W + bias)
// MODE 1: C = (A@W) * dinv[row]
// MODE 2: C = relu((A+A2)@W + bias)
// swapped operands: mfma(A_op=W-frag[c][k], B_op=X-frag[row][k]) -> D[c-dim=reg, row-dim=lane&15]
template<int MODE>
__global__ __launch_bounds__(256) void k_gemm(const unsigned short* __restrict__ A,
        const unsigned short* __restrict__ A2, const unsigned short* __restrict__ Wt,
        const float* __restrict__ bias, const float* __restrict__ dinv,
        unsigned short* __restrict__ C) {
    __shared__ unsigned short sW[16384];   // 32 KB, same (pre-swizzled) layout as Wt
    const int t = threadIdx.x;
    {   // linear stage: conflict-free
        const float4* s = reinterpret_cast<const float4*>(Wt);
        float4* d = reinterpret_cast<float4*>(sW);
        #pragma unroll
        for (int i = 0; i < 8; ++i) d[i*256 + t] = s[i*256 + t];
    }
    __syncthreads();

    const int lane = t & 63, w = t >> 6;
    const int wrow = (w & 1) << 5;     // 0 / 32
    const int wcol = (w >> 1) << 6;    // 0 / 64
    const size_t row0 = (size_t)blockIdx.x * 64;
    const int l15 = lane & 15, l4 = lane >> 4;

    size_t rbase[2];
    rbase[0] = row0 + wrow + l15;
    rbase[1] = rbase[0] + 16;

    f32x4 acc[2][4];
    #pragma unroll
    for (int i = 0; i < 2; ++i)
        #pragma unroll
        for (int j = 0; j < 4; ++j) acc[i][j] = (f32x4){0.f, 0.f, 0.f, 0.f};

    #pragma unroll
    for (int kk = 0; kk < 4; ++kk) {
        bf16x8 xf[2];
        #pragma unroll
        for (int f2 = 0; f2 < 2; ++f2) {
            const unsigned short* ap = A + (rbase[f2] << 7) + (kk << 5) + (l4 << 3);
            if (MODE == 2) {
                bf16x8 a = *reinterpret_cast<const bf16x8*>(ap);
                bf16x8 b = *reinterpret_cast<const bf16x8*>(A2 + (rbase[f2] << 7) + (kk << 5) + (l4 << 3));
                bf16x8 r;
                #pragma unroll
                for (int j = 0; j < 8; ++j) r[j] = (short)f2bf(bfs(a[j]) + bfs(b[j]));
                xf[f2] = r;
            } else {
                xf[f2] = *reinterpret_cast<const bf16x8*>(ap);
            }
        }
        #pragma unroll
        for (int f = 0; f < 4; ++f) {
            int c = wcol + f*16 + l15;
            int off = c*128 + (((kk*4 + l4) ^ (c & 7)) << 3);
            bf16x8 wf = *reinterpret_cast<const bf16x8*>(&sW[off]);
            #pragma unroll
            for (int f2 = 0; f2 < 2; ++f2)
                acc[f2][f] = __builtin_amdgcn_mfma_f32_16x16x32_bf16(wf, xf[f2], acc[f2][f], 0, 0, 0);
        }
    }

    float dv[2];
    if (MODE == 1) { dv[0] = dinv[rbase[0]]; dv[1] = dinv[rbase[1]]; }

    #pragma unroll
    for (int f = 0; f < 4; ++f) {
        int colb = wcol + f*16 + (l4 << 2);   // 4 consecutive cols per lane
        float4 bs = make_float4(0.f, 0.f, 0.f, 0.f);
        if (MODE != 1) bs = ld4(bias + colb);
        #pragma unroll
        for (int f2 = 0; f2 < 2; ++f2) {
            f32x4 v = acc[f2][f];
            float x0, x1, x2, x3;
            if (MODE == 1) {
                float d = dv[f2];
                x0 = v[0]*d; x1 = v[1]*d; x2 = v[2]*d; x3 = v[3]*d;
            } else {
                x0 = fmaxf(v[0] + bs.x, 0.f); x1 = fmaxf(v[1] + bs.y, 0.f);
                x2 = fmaxf(v[2] + bs.z, 0.f); x3 = fmaxf(v[3] + bs.w, 0.f);
            }
            uint2 p; p.x = pack2(x0, x1); p.y = pack2(x2, x3);
            *reinterpret_cast<uint2*>(C + (rbase[f2] << 7) + colb) = p;
        }
    }
}

// ---------------- aggregation (pull via CSR, bf16 in/out) ----------------
__global__ __launch_bounds__(256) void k_agg(const unsigned short* __restrict__ h,
        const int* __restrict__ adj, const int* __restrict__ offs,
        const float* __restrict__ dinv, const float* __restrict__ bias,
        unsigned short* __restrict__ out) {
    int wid = blockIdx.x * 4 + (threadIdx.x >> 6);   // one wave per node
    int lane = threadIdx.x & 63;
    int g = wid >> 11, n = wid & (N-1);
    const unsigned short* hg = h + ((size_t)(g << 11) << 7);
    int st = offs[g*(N+1) + n];
    int en = offs[g*(N+1) + n + 1];
    const int* al = adj + (size_t)g*E;
    const int c2 = lane << 1;
    unsigned us = *reinterpret_cast<const unsigned*>(hg + ((size_t)n << 7) + c2);
    float ax = bflo(us), ay = bfhi(us);   // self-loop term
    int e = st;
    for (; e + 4 <= en; e += 4) {
        int s0 = al[e], s1 = al[e+1], s2 = al[e+2], s3 = al[e+3];
        unsigned u0 = *reinterpret_cast<const unsigned*>(hg + ((size_t)s0 << 7) + c2);
        unsigned u1 = *reinterpret_cast<const unsigned*>(hg + ((size_t)s1 << 7) + c2);
        unsigned u2 = *reinterpret_cast<const unsigned*>(hg + ((size_t)s2 << 7) + c2);
        unsigned u3 = *reinterpret_cast<const unsigned*>(hg + ((size_t)s3 << 7) + c2);
        ax += (bflo(u0) + bflo(u1)) + (bflo(u2) + bflo(u3));
        ay += (bfhi(u0) + bfhi(u1)) + (bfhi(u2) + bfhi(u3));
    }
    for (; e < en; ++e) {
        unsigned u = *reinterpret_cast<const unsigned*>(hg + ((size_t)al[e] << 7) + c2);
        ax += bflo(u); ay += bfhi(u);
    }
    float d = dinv[wid];
    unsigned pv = pack2(fmaxf(ax*d + bias[c2], 0.f), fmaxf(ay*d + bias[c2+1], 0.f));
    *reinterpret_cast<unsigned*>(out + ((size_t)wid << 7) + c2) = pv;
}

// ---------------- mean over nodes (partial + atomic) ----------------
__global__ __launch_bounds__(256) void k_mean(const unsigned short* __restrict__ y,
                                              float* __restrict__ tgt) {
    int g = blockIdx.x >> 3, part = blockIdx.x & 7;
    int t = threadIdx.x, gq = t >> 6, lane = t & 63;
    int c2 = lane << 1;
    const unsigned short* p = y + (((size_t)g*N + part*256 + gq*64) << 7) + c2;
    float sx = 0.f, sy = 0.f;
    for (int n = 0; n < 64; ++n) {
        unsigned u = *reinterpret_cast<const unsigned*>(p + ((size_t)n << 7));
        sx += bflo(u); sy += bfhi(u);
    }
    atomicAdd(&tgt[g*128 + c2], sx);
    atomicAdd(&tgt[g*128 + c2 + 1], sy);
}

// ---------------- logits + log_softmax ----------------
__global__ void k_final(const float* __restrict__ tgt, const float* __restrict__ lw,
        const float* __restrict__ lb, float* __restrict__ outp) {
    int g = blockIdx.x * blockDim.x + threadIdx.x;
    if (g >= G) return;
    float l0 = lb[0], l1 = lb[1];
    for (int c = 0; c < 128; ++c) {
        float v = tgt[g*128 + c] * (1.0f/2048.0f);
        l0 += v * lw[c*2];
        l1 += v * lw[c*2 + 1];
    }
    float m = fmaxf(l0, l1);
    float lse = m + logf(expf(l0 - m) + expf(l1 - m));
    outp[g*2]         = l0 - lse;
    outp[g*2 + 1]     = l1 - lse;
    outp[G*2 + g*2]     = l0;
    outp[G*2 + g*2 + 1] = l1;
}

extern "C" void kernel_launch(void* const* d_in, const int* in_sizes, int n_in,
                              void* d_out, int out_size, void* d_ws, size_t ws_size,
                              hipStream_t stream) {
    const float* all_features = (const float*)d_in[0];
    const int*   fidx = (const int*)d_in[1];
    const int*   ei   = (const int*)d_in[2];
    // d_in[3] = action (always 2 -> 3 GCN layers)
    const float* wres = (const float*)d_in[4];
    const float* bres = (const float*)d_in[5];
    const float* gw   = (const float*)d_in[6];
    const float* gb   = (const float*)d_in[7];
    const float* wfc  = (const float*)d_in[8];
    const float* bfc  = (const float*)d_in[9];
    const float* lw   = (const float*)d_in[10];
    const float* lb   = (const float*)d_in[11];
    float* out = (float*)d_out;

    char* ws = (char*)d_ws;
    size_t o = 0;
    auto alloc = [&](size_t bytes) { char* p = ws + o; o += (bytes + 255) & ~(size_t)255; return p; };
    unsigned short* X  = (unsigned short*)alloc((size_t)GN*128*2);   // node features (bf16)
    unsigned short* Hb = (unsigned short*)alloc((size_t)GN*128*2);   // h' / final y (bf16)
    unsigned short* X1 = (unsigned short*)alloc((size_t)GN*128*2);   // residual (bf16)
    unsigned short* Wt = (unsigned short*)alloc((size_t)5*16384*2);  // prepped weights
    int*   adj    = (int*)alloc((size_t)G*E*4);
    int*   cnt    = (int*)alloc((size_t)GN*4);
    int*   offs   = (int*)alloc((size_t)G*(N+1)*4);
    int*   cursor = (int*)alloc((size_t)GN*4);
    float* dinv   = (float*)alloc((size_t)GN*4);
    float* tgt    = (float*)alloc((size_t)G*128*4);

    hipMemsetAsync(cnt, 0, (size_t)GN*4, stream);
    hipMemsetAsync(tgt, 0, (size_t)G*128*4, stream);

    k_prepw<<<40, 256, 0, stream>>>(wres, gw, wfc, Wt);
    k_count<<<G*E/256, 256, 0, stream>>>(ei, cnt);
    k_scan<<<G, 256, 0, stream>>>(cnt, offs, cursor, dinv);
    k_fill<<<G*E/256, 256, 0, stream>>>(ei, cursor, adj);
    k_gather<<<GN*32/256, 256, 0, stream>>>(all_features, fidx, X);

    // residual: X1 = relu(X @ Wres + bres)
    k_gemm<0><<<GN/64, 256, 0, stream>>>(X, nullptr, Wt, bres, nullptr, X1);

    // 3 GCN layers
    for (int l = 0; l < 3; ++l) {
        k_gemm<1><<<GN/64, 256, 0, stream>>>(X, nullptr, Wt + (size_t)(1+l)*16384, nullptr, dinv, Hb);
        k_agg<<<GN/4, 256, 0, stream>>>(Hb, adj, offs, dinv, gb + (size_t)l*128, X);
    }

    // fc1: Hb = relu((X + X1) @ Wfc + bfc)
    k_gemm<2><<<GN/64, 256, 0, stream>>>(X, X1, Wt + (size_t)4*16384, bfc, nullptr, Hb);

    k_mean<<<G*8, 256, 0, stream>>>(Hb, tgt);
    k_final<<<1, 64, 0, stream>>>(tgt, lw, lb, out);
}

// Round 3
// 437.134 us; speedup vs baseline: 2.0480x; 1.3046x over previous
//
#include <hip/hip_runtime.h>

#define G 64
#define N 2048
#define E 32768
#define GN (G*N)   // 131072

typedef __attribute__((ext_vector_type(8))) short bf16x8;
typedef __attribute__((ext_vector_type(4))) float f32x4;

__device__ __forceinline__ float4 ld4(const float* p) { return *reinterpret_cast<const float4*>(p); }
__device__ __forceinline__ unsigned short f2bf(float x) {   // RNE
    unsigned u = __float_as_uint(x);
    u += 0x7FFF + ((u >> 16) & 1);
    return (unsigned short)(u >> 16);
}
__device__ __forceinline__ unsigned pack2(float a, float b) {
    return (unsigned)f2bf(a) | ((unsigned)f2bf(b) << 16);
}
__device__ __forceinline__ float bflo(unsigned u) { return __uint_as_float(u << 16); }
__device__ __forceinline__ float bfhi(unsigned u) { return __uint_as_float(u & 0xFFFF0000u); }
__device__ __forceinline__ float bfs(short s) { return __uint_as_float(((unsigned)(unsigned short)s) << 16); }

// ---------------- fused CSR build: count + scan + fill, 1 block/graph ----------------
__global__ __launch_bounds__(1024) void k_csr(const int* __restrict__ ei,
        int* __restrict__ offs, int* __restrict__ adj, float* __restrict__ dinv) {
    int g = blockIdx.x, t = threadIdx.x;
    __shared__ int scnt[2048];
    __shared__ int swave[16];
    scnt[t] = 0; scnt[t + 1024] = 0;
    __syncthreads();
    const int* srcp = ei + (size_t)g*2*E;
    const int* dstp = srcp + E;
    for (int e = t; e < E; e += 1024) atomicAdd(&scnt[dstp[e]], 1);
    __syncthreads();
    // scan: thread t owns nodes 2t, 2t+1
    int a = scnt[2*t], b = scnt[2*t + 1];
    int s = a + b;
    int lane = t & 63, wid = t >> 6;
    #pragma unroll
    for (int d = 1; d < 64; d <<= 1) { int v = __shfl_up(s, d); if (lane >= d) s += v; }
    if (lane == 63) swave[wid] = s;
    __syncthreads();
    if (t < 16) {
        int v = swave[t];
        #pragma unroll
        for (int d = 1; d < 16; d <<= 1) { int u = __shfl_up(v, d); if (t >= d) v += u; }
        swave[t] = v;
    }
    __syncthreads();
    int woff = (wid == 0) ? 0 : swave[wid - 1];
    int e0 = woff + s - (a + b);   // exclusive offset of node 2t
    int e1 = e0 + a;
    offs[g*(N+1) + 2*t]     = e0;
    offs[g*(N+1) + 2*t + 1] = e1;
    if (t == 0) offs[g*(N+1) + N] = E;
    dinv[(g<<11) + 2*t]     = rsqrtf((float)(a + 1));
    dinv[(g<<11) + 2*t + 1] = rsqrtf((float)(b + 1));
    scnt[2*t] = e0; scnt[2*t + 1] = e1;   // cursor (own elements only -> no race)
    __syncthreads();
    for (int e = t; e < E; e += 1024) {
        int dst = dstp[e];
        int pos = atomicAdd(&scnt[dst], 1);
        adj[(size_t)g*E + pos] = srcp[e];
    }
}

// ---------------- gather x0 (fp32 table -> bf16) ----------------
__global__ void k_gather(const float* __restrict__ tab, const int* __restrict__ fidx,
                         unsigned short* __restrict__ X) {
    int i = blockIdx.x * 256 + threadIdx.x;   // GN*32 threads, 4 cols each
    int row = i >> 5, q = i & 31;
    int f = fidx[row];
    float4 v = ld4(tab + (size_t)f*128 + q*4);
    uint2 p; p.x = pack2(v.x, v.y); p.y = pack2(v.z, v.w);
    *reinterpret_cast<uint2*>(X + ((size_t)row << 7) + q*4) = p;
}

// ---------------- weight prep: fp32 [k][c] -> bf16 Wt[c][k], k-chunk XOR-swizzled ----------------
__global__ void k_prepw(const float* __restrict__ wres, const float* __restrict__ gw,
                        const float* __restrict__ wfc, unsigned short* __restrict__ Wt) {
    int b = blockIdx.x;                // 40 blocks: 5 matrices x 8
    int m = b >> 3;
    int tid = (b & 7) * 256 + threadIdx.x;   // 0..2047
    const float* src = (m == 0) ? wres : (m < 4 ? gw + (size_t)(m-1)*16384 : wfc);
    int c = tid >> 4, q = tid & 15;
    float v[8];
    #pragma unroll
    for (int j = 0; j < 8; ++j) v[j] = src[(q*8 + j)*128 + c];
    uint4 p;
    p.x = pack2(v[0], v[1]); p.y = pack2(v[2], v[3]);
    p.z = pack2(v[4], v[5]); p.w = pack2(v[6], v[7]);
    *reinterpret_cast<uint4*>(Wt + (size_t)m*16384 + c*128 + ((q ^ (c & 7)) << 3)) = p;
}

// ---------------- MFMA GEMM: 128-row tiles ----------------
// MODE 0: C = relu(A@W + bias)
// MODE 1: C = (A@W) * dinv[row]
// MODE 2: colsum(relu((A+A2)@W + bias)) -> atomicAdd tgt  (no C write)
template<int MODE>
__global__ __launch_bounds__(256) void k_gemm(const unsigned short* __restrict__ A,
        const unsigned short* __restrict__ A2, const unsigned short* __restrict__ Wt,
        const float* __restrict__ bias, const float* __restrict__ dinv,
        unsigned short* __restrict__ C, float* __restrict__ tgt) {
    __shared__ unsigned short sW[16384];   // 32 KB, pre-swizzled
    const int t = threadIdx.x;
    {
        const float4* s = reinterpret_cast<const float4*>(Wt);
        float4* d = reinterpret_cast<float4*>(sW);
        #pragma unroll
        for (int i = 0; i < 8; ++i) d[i*256 + t] = s[i*256 + t];
    }
    __syncthreads();

    const int lane = t & 63, w = t >> 6;
    const int wrow = (w & 1) << 6;     // 0 / 64
    const int wcol = (w >> 1) << 6;    // 0 / 64
    const size_t row0 = (size_t)blockIdx.x * 128;
    const int l15 = lane & 15, l4 = lane >> 4;

    size_t rbase[4];
    #pragma unroll
    for (int f2 = 0; f2 < 4; ++f2) rbase[f2] = row0 + wrow + f2*16 + l15;

    f32x4 acc[4][4];
    #pragma unroll
    for (int i = 0; i < 4; ++i)
        #pragma unroll
        for (int j = 0; j < 4; ++j) acc[i][j] = (f32x4){0.f, 0.f, 0.f, 0.f};

    #pragma unroll
    for (int kk = 0; kk < 4; ++kk) {
        bf16x8 xf[4];
        #pragma unroll
        for (int f2 = 0; f2 < 4; ++f2) {
            const unsigned short* ap = A + (rbase[f2] << 7) + (kk << 5) + (l4 << 3);
            if (MODE == 2) {
                bf16x8 x = *reinterpret_cast<const bf16x8*>(ap);
                bf16x8 y = *reinterpret_cast<const bf16x8*>(A2 + (rbase[f2] << 7) + (kk << 5) + (l4 << 3));
                bf16x8 r;
                #pragma unroll
                for (int j = 0; j < 8; ++j) r[j] = (short)f2bf(bfs(x[j]) + bfs(y[j]));
                xf[f2] = r;
            } else {
                xf[f2] = *reinterpret_cast<const bf16x8*>(ap);
            }
        }
        #pragma unroll
        for (int f = 0; f < 4; ++f) {
            int c = wcol + f*16 + l15;
            int off = c*128 + (((kk*4 + l4) ^ (c & 7)) << 3);
            bf16x8 wf = *reinterpret_cast<const bf16x8*>(&sW[off]);
            #pragma unroll
            for (int f2 = 0; f2 < 4; ++f2)
                acc[f2][f] = __builtin_amdgcn_mfma_f32_16x16x32_bf16(wf, xf[f2], acc[f2][f], 0, 0, 0);
        }
    }

    if (MODE == 2) {
        // fused mean: colsum of relu(acc+bias) over this block's 128 rows
        float cs[4][4];
        #pragma unroll
        for (int f = 0; f < 4; ++f) {
            int colb = wcol + f*16 + (l4 << 2);
            float4 bs = ld4(bias + colb);
            #pragma unroll
            for (int j = 0; j < 4; ++j) cs[f][j] = 0.f;
            #pragma unroll
            for (int f2 = 0; f2 < 4; ++f2) {
                cs[f][0] += fmaxf(acc[f2][f][0] + bs.x, 0.f);
                cs[f][1] += fmaxf(acc[f2][f][1] + bs.y, 0.f);
                cs[f][2] += fmaxf(acc[f2][f][2] + bs.z, 0.f);
                cs[f][3] += fmaxf(acc[f2][f][3] + bs.w, 0.f);
            }
        }
        #pragma unroll
        for (int d = 1; d < 16; d <<= 1)
            #pragma unroll
            for (int f = 0; f < 4; ++f)
                #pragma unroll
                for (int j = 0; j < 4; ++j)
                    cs[f][j] += __shfl_xor(cs[f][j], d);
        if (l15 == 0) {
            int g = (int)(row0 >> 11);
            #pragma unroll
            for (int f = 0; f < 4; ++f)
                #pragma unroll
                for (int j = 0; j < 4; ++j)
                    atomicAdd(&tgt[g*128 + wcol + f*16 + (l4 << 2) + j], cs[f][j]);
        }
        return;
    }

    float dv[4];
    if (MODE == 1) {
        #pragma unroll
        for (int f2 = 0; f2 < 4; ++f2) dv[f2] = dinv[rbase[f2]];
    }
    #pragma unroll
    for (int f = 0; f < 4; ++f) {
        int colb = wcol + f*16 + (l4 << 2);
        float4 bs = make_float4(0.f, 0.f, 0.f, 0.f);
        if (MODE != 1) bs = ld4(bias + colb);
        #pragma unroll
        for (int f2 = 0; f2 < 4; ++f2) {
            f32x4 v = acc[f2][f];
            float x0, x1, x2, x3;
            if (MODE == 1) {
                float d = dv[f2];
                x0 = v[0]*d; x1 = v[1]*d; x2 = v[2]*d; x3 = v[3]*d;
            } else {
                x0 = fmaxf(v[0] + bs.x, 0.f); x1 = fmaxf(v[1] + bs.y, 0.f);
                x2 = fmaxf(v[2] + bs.z, 0.f); x3 = fmaxf(v[3] + bs.w, 0.f);
            }
            uint2 p; p.x = pack2(x0, x1); p.y = pack2(x2, x3);
            *reinterpret_cast<uint2*>(C + (rbase[f2] << 7) + colb) = p;
        }
    }
}

// ---------------- aggregation (pull via CSR, bf16 in/out) ----------------
__global__ __launch_bounds__(256) void k_agg(const unsigned short* __restrict__ h,
        const int* __restrict__ adj, const int* __restrict__ offs,
        const float* __restrict__ dinv, const float* __restrict__ bias,
        unsigned short* __restrict__ out) {
    int wid = blockIdx.x * 4 + (threadIdx.x >> 6);   // one wave per node
    int lane = threadIdx.x & 63;
    int g = wid >> 11, n = wid & (N-1);
    const unsigned short* hg = h + ((size_t)(g << 11) << 7);
    int st = offs[g*(N+1) + n];
    int en = offs[g*(N+1) + n + 1];
    const int* al = adj + (size_t)g*E;
    const int c2 = lane << 1;
    unsigned us = *reinterpret_cast<const unsigned*>(hg + ((size_t)n << 7) + c2);
    float ax = bflo(us), ay = bfhi(us);   // self-loop term
    int e = st;
    for (; e + 4 <= en; e += 4) {
        int s0 = al[e], s1 = al[e+1], s2 = al[e+2], s3 = al[e+3];
        unsigned u0 = *reinterpret_cast<const unsigned*>(hg + ((size_t)s0 << 7) + c2);
        unsigned u1 = *reinterpret_cast<const unsigned*>(hg + ((size_t)s1 << 7) + c2);
        unsigned u2 = *reinterpret_cast<const unsigned*>(hg + ((size_t)s2 << 7) + c2);
        unsigned u3 = *reinterpret_cast<const unsigned*>(hg + ((size_t)s3 << 7) + c2);
        ax += (bflo(u0) + bflo(u1)) + (bflo(u2) + bflo(u3));
        ay += (bfhi(u0) + bfhi(u1)) + (bfhi(u2) + bfhi(u3));
    }
    for (; e < en; ++e) {
        unsigned u = *reinterpret_cast<const unsigned*>(hg + ((size_t)al[e] << 7) + c2);
        ax += bflo(u); ay += bfhi(u);
    }
    float d = dinv[wid];
    unsigned pv = pack2(fmaxf(ax*d + bias[c2], 0.f), fmaxf(ay*d + bias[c2+1], 0.f));
    *reinterpret_cast<unsigned*>(out + ((size_t)wid << 7) + c2) = pv;
}

// ---------------- logits + log_softmax: one wave per graph ----------------
__global__ __launch_bounds__(64) void k_final(const float* __restrict__ tgt,
        const float* __restrict__ lw, const float* __restrict__ lb, float* __restrict__ outp) {
    int g = blockIdx.x, lane = threadIdx.x;
    float l0 = 0.f, l1 = 0.f;
    #pragma unroll
    for (int c = lane; c < 128; c += 64) {
        float v = tgt[g*128 + c] * (1.0f/2048.0f);
        l0 += v * lw[c*2];
        l1 += v * lw[c*2 + 1];
    }
    #pragma unroll
    for (int d = 32; d; d >>= 1) { l0 += __shfl_xor(l0, d); l1 += __shfl_xor(l1, d); }
    if (lane == 0) {
        l0 += lb[0]; l1 += lb[1];
        float m = fmaxf(l0, l1);
        float lse = m + logf(expf(l0 - m) + expf(l1 - m));
        outp[g*2]         = l0 - lse;
        outp[g*2 + 1]     = l1 - lse;
        outp[G*2 + g*2]     = l0;
        outp[G*2 + g*2 + 1] = l1;
    }
}

extern "C" void kernel_launch(void* const* d_in, const int* in_sizes, int n_in,
                              void* d_out, int out_size, void* d_ws, size_t ws_size,
                              hipStream_t stream) {
    const float* all_features = (const float*)d_in[0];
    const int*   fidx = (const int*)d_in[1];
    const int*   ei   = (const int*)d_in[2];
    // d_in[3] = action (always 2 -> 3 GCN layers)
    const float* wres = (const float*)d_in[4];
    const float* bres = (const float*)d_in[5];
    const float* gw   = (const float*)d_in[6];
    const float* gb   = (const float*)d_in[7];
    const float* wfc  = (const float*)d_in[8];
    const float* bfc  = (const float*)d_in[9];
    const float* lw   = (const float*)d_in[10];
    const float* lb   = (const float*)d_in[11];
    float* out = (float*)d_out;

    char* ws = (char*)d_ws;
    size_t o = 0;
    auto alloc = [&](size_t bytes) { char* p = ws + o; o += (bytes + 255) & ~(size_t)255; return p; };
    unsigned short* X  = (unsigned short*)alloc((size_t)GN*128*2);
    unsigned short* Hb = (unsigned short*)alloc((size_t)GN*128*2);
    unsigned short* X1 = (unsigned short*)alloc((size_t)GN*128*2);
    unsigned short* Wt = (unsigned short*)alloc((size_t)5*16384*2);
    int*   adj  = (int*)alloc((size_t)G*E*4);
    int*   offs = (int*)alloc((size_t)G*(N+1)*4);
    float* dinv = (float*)alloc((size_t)GN*4);
    float* tgt  = (float*)alloc((size_t)G*128*4);

    hipMemsetAsync(tgt, 0, (size_t)G*128*4, stream);

    k_prepw<<<40, 256, 0, stream>>>(wres, gw, wfc, Wt);
    k_csr<<<G, 1024, 0, stream>>>(ei, offs, adj, dinv);
    k_gather<<<GN*32/256, 256, 0, stream>>>(all_features, fidx, X);

    // residual: X1 = relu(X @ Wres + bres)
    k_gemm<0><<<GN/128, 256, 0, stream>>>(X, nullptr, Wt, bres, nullptr, X1, nullptr);

    // 3 GCN layers
    for (int l = 0; l < 3; ++l) {
        k_gemm<1><<<GN/128, 256, 0, stream>>>(X, nullptr, Wt + (size_t)(1+l)*16384, nullptr, dinv, Hb, nullptr);
        k_agg<<<GN/4, 256, 0, stream>>>(Hb, adj, offs, dinv, gb + (size_t)l*128, X);
    }

    // fc1 + mean fused: atomicAdd col-sums of relu((X+X1)@Wfc+bfc) into tgt
    k_gemm<2><<<GN/128, 256, 0, stream>>>(X, X1, Wt + (size_t)4*16384, bfc, nullptr, nullptr, tgt);

    k_final<<<G, 64, 0, stream>>>(tgt, lw, lb, out);
}

// Round 4
// 389.918 us; speedup vs baseline: 2.2960x; 1.1211x over previous
//
#include <hip/hip_runtime.h>

#define G 64
#define N 2048
#define E 32768
#define GN (G*N)   // 131072

typedef __attribute__((ext_vector_type(8))) short bf16x8;
typedef __attribute__((ext_vector_type(4))) float f32x4;

__device__ __forceinline__ float4 ld4(const float* p) { return *reinterpret_cast<const float4*>(p); }
__device__ __forceinline__ unsigned short f2bf(float x) {   // RNE
    unsigned u = __float_as_uint(x);
    u += 0x7FFF + ((u >> 16) & 1);
    return (unsigned short)(u >> 16);
}
__device__ __forceinline__ unsigned pack2(float a, float b) {
    return (unsigned)f2bf(a) | ((unsigned)f2bf(b) << 16);
}
__device__ __forceinline__ float bflo(unsigned u) { return __uint_as_float(u << 16); }
__device__ __forceinline__ float bfhi(unsigned u) { return __uint_as_float(u & 0xFFFF0000u); }
__device__ __forceinline__ float bfs(short s) { return __uint_as_float(((unsigned)(unsigned short)s) << 16); }

// bijective XCD swizzle (grid % 8 == 0): XCD x = bid&7 gets contiguous chunk
__device__ __forceinline__ int swz(int bid, int chunk) { return (bid & 7) * chunk + (bid >> 3); }

// ---------------- fused CSR build: count + scan + fill, 1 block/graph ----------------
__global__ __launch_bounds__(1024) void k_csr(const int* __restrict__ ei,
        int* __restrict__ offs, int* __restrict__ adj, float* __restrict__ dinv) {
    int g = blockIdx.x, t = threadIdx.x;
    __shared__ int scnt[2048];
    __shared__ int swave[16];
    scnt[t] = 0; scnt[t + 1024] = 0;
    __syncthreads();
    const int* srcp = ei + (size_t)g*2*E;
    const int* dstp = srcp + E;
    for (int e = t; e < E; e += 1024) atomicAdd(&scnt[dstp[e]], 1);
    __syncthreads();
    // scan: thread t owns nodes 2t, 2t+1
    int a = scnt[2*t], b = scnt[2*t + 1];
    int s = a + b;
    int lane = t & 63, wid = t >> 6;
    #pragma unroll
    for (int d = 1; d < 64; d <<= 1) { int v = __shfl_up(s, d); if (lane >= d) s += v; }
    if (lane == 63) swave[wid] = s;
    __syncthreads();
    if (t < 16) {
        int v = swave[t];
        #pragma unroll
        for (int d = 1; d < 16; d <<= 1) { int u = __shfl_up(v, d); if (t >= d) v += u; }
        swave[t] = v;
    }
    __syncthreads();
    int woff = (wid == 0) ? 0 : swave[wid - 1];
    int e0 = woff + s - (a + b);   // exclusive offset of node 2t
    int e1 = e0 + a;
    offs[g*(N+1) + 2*t]     = e0;
    offs[g*(N+1) + 2*t + 1] = e1;
    if (t == 0) offs[g*(N+1) + N] = E;
    dinv[(g<<11) + 2*t]     = rsqrtf((float)(a + 1));
    dinv[(g<<11) + 2*t + 1] = rsqrtf((float)(b + 1));
    scnt[2*t] = e0; scnt[2*t + 1] = e1;   // cursor (own elements only -> no race)
    __syncthreads();
    for (int e = t; e < E; e += 1024) {
        int dst = dstp[e];
        int pos = atomicAdd(&scnt[dst], 1);
        adj[(size_t)g*E + pos] = srcp[e];
    }
}

// ---------------- weight prep: fp32 [k][c] -> bf16 Wt[c][k], k-chunk XOR-swizzled ----------------
__global__ void k_prepw(const float* __restrict__ wres, const float* __restrict__ gw,
                        const float* __restrict__ wfc, unsigned short* __restrict__ Wt) {
    int b = blockIdx.x;                // 40 blocks: 5 matrices x 8
    int m = b >> 3;
    int tid = (b & 7) * 256 + threadIdx.x;   // 0..2047
    const float* src = (m == 0) ? wres : (m < 4 ? gw + (size_t)(m-1)*16384 : wfc);
    int c = tid >> 4, q = tid & 15;
    float v[8];
    #pragma unroll
    for (int j = 0; j < 8; ++j) v[j] = src[(q*8 + j)*128 + c];
    uint4 p;
    p.x = pack2(v[0], v[1]); p.y = pack2(v[2], v[3]);
    p.z = pack2(v[4], v[5]); p.w = pack2(v[6], v[7]);
    *reinterpret_cast<uint4*>(Wt + (size_t)m*16384 + c*128 + ((q ^ (c & 7)) << 3)) = p;
}

// ---------------- MFMA GEMM: 128-row tiles, XCD-swizzled ----------------
// MODE 0: C = relu(A@W + bias)
// MODE 1: C = (A@W) * dinv[row]
// MODE 2: colsum(relu((A+A2)@W + bias)) -> atomicAdd tgt  (no C write)
// GATHER: A row r = bf16(tab[fidx[r]])  (fp32 table, on-the-fly convert)
template<int MODE, int GATHER>
__global__ __launch_bounds__(256) void k_gemm(const unsigned short* __restrict__ A,
        const unsigned short* __restrict__ A2, const unsigned short* __restrict__ Wt,
        const float* __restrict__ bias, const float* __restrict__ dinv,
        unsigned short* __restrict__ C, float* __restrict__ tgt,
        const int* __restrict__ fidx, const float* __restrict__ tab) {
    __shared__ unsigned short sW[16384];   // 32 KB, pre-swizzled
    const int t = threadIdx.x;
    {
        const float4* s = reinterpret_cast<const float4*>(Wt);
        float4* d = reinterpret_cast<float4*>(sW);
        #pragma unroll
        for (int i = 0; i < 8; ++i) d[i*256 + t] = s[i*256 + t];
    }
    __syncthreads();

    const int lane = t & 63, w = t >> 6;
    const int wrow = (w & 1) << 6;     // 0 / 64
    const int wcol = (w >> 1) << 6;    // 0 / 64
    const size_t row0 = (size_t)swz(blockIdx.x, GN/128/8) * 128;
    const int l15 = lane & 15, l4 = lane >> 4;

    size_t rbase[4];
    #pragma unroll
    for (int f2 = 0; f2 < 4; ++f2) rbase[f2] = row0 + wrow + f2*16 + l15;

    const float* rowp[4];
    if (GATHER) {
        #pragma unroll
        for (int f2 = 0; f2 < 4; ++f2) rowp[f2] = tab + (size_t)fidx[rbase[f2]] * 128;
    }

    f32x4 acc[4][4];
    #pragma unroll
    for (int i = 0; i < 4; ++i)
        #pragma unroll
        for (int j = 0; j < 4; ++j) acc[i][j] = (f32x4){0.f, 0.f, 0.f, 0.f};

    #pragma unroll
    for (int kk = 0; kk < 4; ++kk) {
        bf16x8 xf[4];
        #pragma unroll
        for (int f2 = 0; f2 < 4; ++f2) {
            if (GATHER) {
                int col = (kk << 5) + (l4 << 3);
                float4 u = ld4(rowp[f2] + col);
                float4 v = ld4(rowp[f2] + col + 4);
                bf16x8 r;
                r[0] = (short)f2bf(u.x); r[1] = (short)f2bf(u.y);
                r[2] = (short)f2bf(u.z); r[3] = (short)f2bf(u.w);
                r[4] = (short)f2bf(v.x); r[5] = (short)f2bf(v.y);
                r[6] = (short)f2bf(v.z); r[7] = (short)f2bf(v.w);
                xf[f2] = r;
            } else {
                const unsigned short* ap = A + (rbase[f2] << 7) + (kk << 5) + (l4 << 3);
                if (MODE == 2) {
                    bf16x8 x = *reinterpret_cast<const bf16x8*>(ap);
                    bf16x8 y = *reinterpret_cast<const bf16x8*>(A2 + (rbase[f2] << 7) + (kk << 5) + (l4 << 3));
                    bf16x8 r;
                    #pragma unroll
                    for (int j = 0; j < 8; ++j) r[j] = (short)f2bf(bfs(x[j]) + bfs(y[j]));
                    xf[f2] = r;
                } else {
                    xf[f2] = *reinterpret_cast<const bf16x8*>(ap);
                }
            }
        }
        #pragma unroll
        for (int f = 0; f < 4; ++f) {
            int c = wcol + f*16 + l15;
            int off = c*128 + (((kk*4 + l4) ^ (c & 7)) << 3);
            bf16x8 wf = *reinterpret_cast<const bf16x8*>(&sW[off]);
            #pragma unroll
            for (int f2 = 0; f2 < 4; ++f2)
                acc[f2][f] = __builtin_amdgcn_mfma_f32_16x16x32_bf16(wf, xf[f2], acc[f2][f], 0, 0, 0);
        }
    }

    if (MODE == 2) {
        // fused mean: colsum of relu(acc+bias) over this block's 128 rows
        float cs[4][4];
        #pragma unroll
        for (int f = 0; f < 4; ++f) {
            int colb = wcol + f*16 + (l4 << 2);
            float4 bs = ld4(bias + colb);
            #pragma unroll
            for (int j = 0; j < 4; ++j) cs[f][j] = 0.f;
            #pragma unroll
            for (int f2 = 0; f2 < 4; ++f2) {
                cs[f][0] += fmaxf(acc[f2][f][0] + bs.x, 0.f);
                cs[f][1] += fmaxf(acc[f2][f][1] + bs.y, 0.f);
                cs[f][2] += fmaxf(acc[f2][f][2] + bs.z, 0.f);
                cs[f][3] += fmaxf(acc[f2][f][3] + bs.w, 0.f);
            }
        }
        #pragma unroll
        for (int d = 1; d < 16; d <<= 1)
            #pragma unroll
            for (int f = 0; f < 4; ++f)
                #pragma unroll
                for (int j = 0; j < 4; ++j)
                    cs[f][j] += __shfl_xor(cs[f][j], d);
        if (l15 == 0) {
            int g = (int)(row0 >> 11);
            #pragma unroll
            for (int f = 0; f < 4; ++f)
                #pragma unroll
                for (int j = 0; j < 4; ++j)
                    atomicAdd(&tgt[g*128 + wcol + f*16 + (l4 << 2) + j], cs[f][j]);
        }
        return;
    }

    float dv[4];
    if (MODE == 1) {
        #pragma unroll
        for (int f2 = 0; f2 < 4; ++f2) dv[f2] = dinv[rbase[f2]];
    }
    #pragma unroll
    for (int f = 0; f < 4; ++f) {
        int colb = wcol + f*16 + (l4 << 2);
        float4 bs = make_float4(0.f, 0.f, 0.f, 0.f);
        if (MODE != 1) bs = ld4(bias + colb);
        #pragma unroll
        for (int f2 = 0; f2 < 4; ++f2) {
            f32x4 v = acc[f2][f];
            float x0, x1, x2, x3;
            if (MODE == 1) {
                float d = dv[f2];
                x0 = v[0]*d; x1 = v[1]*d; x2 = v[2]*d; x3 = v[3]*d;
            } else {
                x0 = fmaxf(v[0] + bs.x, 0.f); x1 = fmaxf(v[1] + bs.y, 0.f);
                x2 = fmaxf(v[2] + bs.z, 0.f); x3 = fmaxf(v[3] + bs.w, 0.f);
            }
            uint2 p; p.x = pack2(x0, x1); p.y = pack2(x2, x3);
            *reinterpret_cast<uint2*>(C + (rbase[f2] << 7) + colb) = p;
        }
    }
}

// ---------------- aggregation (pull via CSR, bf16 in/out), XCD-swizzled ----------------
__global__ __launch_bounds__(256) void k_agg(const unsigned short* __restrict__ h,
        const int* __restrict__ adj, const int* __restrict__ offs,
        const float* __restrict__ dinv, const float* __restrict__ bias,
        unsigned short* __restrict__ out) {
    int bid = swz(blockIdx.x, GN/4/8);
    int wid = bid * 4 + (threadIdx.x >> 6);   // one wave per node
    int lane = threadIdx.x & 63;
    int g = wid >> 11, n = wid & (N-1);
    const unsigned short* hg = h + ((size_t)(g << 11) << 7);
    int st = offs[g*(N+1) + n];
    int en = offs[g*(N+1) + n + 1];
    const int* al = adj + (size_t)g*E;
    const int c2 = lane << 1;
    unsigned us = *reinterpret_cast<const unsigned*>(hg + ((size_t)n << 7) + c2);
    float ax = bflo(us), ay = bfhi(us);   // self-loop term
    int e = st;
    for (; e + 4 <= en; e += 4) {
        int s0 = al[e], s1 = al[e+1], s2 = al[e+2], s3 = al[e+3];
        unsigned u0 = *reinterpret_cast<const unsigned*>(hg + ((size_t)s0 << 7) + c2);
        unsigned u1 = *reinterpret_cast<const unsigned*>(hg + ((size_t)s1 << 7) + c2);
        unsigned u2 = *reinterpret_cast<const unsigned*>(hg + ((size_t)s2 << 7) + c2);
        unsigned u3 = *reinterpret_cast<const unsigned*>(hg + ((size_t)s3 << 7) + c2);
        ax += (bflo(u0) + bflo(u1)) + (bflo(u2) + bflo(u3));
        ay += (bfhi(u0) + bfhi(u1)) + (bfhi(u2) + bfhi(u3));
    }
    for (; e < en; ++e) {
        unsigned u = *reinterpret_cast<const unsigned*>(hg + ((size_t)al[e] << 7) + c2);
        ax += bflo(u); ay += bfhi(u);
    }
    float d = dinv[wid];
    unsigned pv = pack2(fmaxf(ax*d + bias[c2], 0.f), fmaxf(ay*d + bias[c2+1], 0.f));
    *reinterpret_cast<unsigned*>(out + ((size_t)wid << 7) + c2) = pv;
}

// ---------------- logits + log_softmax: one wave per graph ----------------
__global__ __launch_bounds__(64) void k_final(const float* __restrict__ tgt,
        const float* __restrict__ lw, const float* __restrict__ lb, float* __restrict__ outp) {
    int g = blockIdx.x, lane = threadIdx.x;
    float l0 = 0.f, l1 = 0.f;
    #pragma unroll
    for (int c = lane; c < 128; c += 64) {
        float v = tgt[g*128 + c] * (1.0f/2048.0f);
        l0 += v * lw[c*2];
        l1 += v * lw[c*2 + 1];
    }
    #pragma unroll
    for (int d = 32; d; d >>= 1) { l0 += __shfl_xor(l0, d); l1 += __shfl_xor(l1, d); }
    if (lane == 0) {
        l0 += lb[0]; l1 += lb[1];
        float m = fmaxf(l0, l1);
        float lse = m + logf(expf(l0 - m) + expf(l1 - m));
        outp[g*2]         = l0 - lse;
        outp[g*2 + 1]     = l1 - lse;
        outp[G*2 + g*2]     = l0;
        outp[G*2 + g*2 + 1] = l1;
    }
}

extern "C" void kernel_launch(void* const* d_in, const int* in_sizes, int n_in,
                              void* d_out, int out_size, void* d_ws, size_t ws_size,
                              hipStream_t stream) {
    const float* all_features = (const float*)d_in[0];
    const int*   fidx = (const int*)d_in[1];
    const int*   ei   = (const int*)d_in[2];
    // d_in[3] = action (always 2 -> 3 GCN layers)
    const float* wres = (const float*)d_in[4];
    const float* bres = (const float*)d_in[5];
    const float* gw   = (const float*)d_in[6];
    const float* gb   = (const float*)d_in[7];
    const float* wfc  = (const float*)d_in[8];
    const float* bfc  = (const float*)d_in[9];
    const float* lw   = (const float*)d_in[10];
    const float* lb   = (const float*)d_in[11];
    float* out = (float*)d_out;

    char* ws = (char*)d_ws;
    size_t o = 0;
    auto alloc = [&](size_t bytes) { char* p = ws + o; o += (bytes + 255) & ~(size_t)255; return p; };
    unsigned short* X  = (unsigned short*)alloc((size_t)GN*128*2);
    unsigned short* Hb = (unsigned short*)alloc((size_t)GN*128*2);
    unsigned short* X1 = (unsigned short*)alloc((size_t)GN*128*2);
    unsigned short* Wt = (unsigned short*)alloc((size_t)5*16384*2);
    int*   adj  = (int*)alloc((size_t)G*E*4);
    int*   offs = (int*)alloc((size_t)G*(N+1)*4);
    float* dinv = (float*)alloc((size_t)GN*4);
    float* tgt  = (float*)alloc((size_t)G*128*4);

    hipMemsetAsync(tgt, 0, (size_t)G*128*4, stream);

    k_prepw<<<40, 256, 0, stream>>>(wres, gw, wfc, Wt);
    k_csr<<<G, 1024, 0, stream>>>(ei, offs, adj, dinv);

    // residual: X1 = relu(gather(X0) @ Wres + bres)   (gather fused)
    k_gemm<0,1><<<GN/128, 256, 0, stream>>>(nullptr, nullptr, Wt, bres, nullptr, X1, nullptr, fidx, all_features);

    // 3 GCN layers (layer 0 gathers X0 on the fly)
    k_gemm<1,1><<<GN/128, 256, 0, stream>>>(nullptr, nullptr, Wt + (size_t)16384, nullptr, dinv, Hb, nullptr, fidx, all_features);
    k_agg<<<GN/4, 256, 0, stream>>>(Hb, adj, offs, dinv, gb, X);
    for (int l = 1; l < 3; ++l) {
        k_gemm<1,0><<<GN/128, 256, 0, stream>>>(X, nullptr, Wt + (size_t)(1+l)*16384, nullptr, dinv, Hb, nullptr, nullptr, nullptr);
        k_agg<<<GN/4, 256, 0, stream>>>(Hb, adj, offs, dinv, gb + (size_t)l*128, X);
    }

    // fc1 + mean fused: atomicAdd col-sums of relu((X+X1)@Wfc+bfc) into tgt
    k_gemm<2,0><<<GN/128, 256, 0, stream>>>(X, X1, Wt + (size_t)4*16384, bfc, nullptr, nullptr, tgt, nullptr, nullptr);

    k_final<<<G, 64, 0, stream>>>(tgt, lw, lb, out);
}

// Round 5
// 370.974 us; speedup vs baseline: 2.4132x; 1.0511x over previous
//
#include <hip/hip_runtime.h>

#define G 64
#define N 2048
#define E 32768
#define GN (G*N)   // 131072

typedef __attribute__((ext_vector_type(8))) short bf16x8;
typedef __attribute__((ext_vector_type(4))) float f32x4;

__device__ __forceinline__ float4 ld4(const float* p) { return *reinterpret_cast<const float4*>(p); }
__device__ __forceinline__ unsigned short f2bf(float x) {   // RNE
    unsigned u = __float_as_uint(x);
    u += 0x7FFF + ((u >> 16) & 1);
    return (unsigned short)(u >> 16);
}
__device__ __forceinline__ unsigned pack2(float a, float b) {
    return (unsigned)f2bf(a) | ((unsigned)f2bf(b) << 16);
}
__device__ __forceinline__ float bflo(unsigned u) { return __uint_as_float(u << 16); }
__device__ __forceinline__ float bfhi(unsigned u) { return __uint_as_float(u & 0xFFFF0000u); }
__device__ __forceinline__ float bfs(short s) { return __uint_as_float(((unsigned)(unsigned short)s) << 16); }

// bijective XCD swizzle (grid % 8 == 0): XCD x = bid&7 gets contiguous chunk
__device__ __forceinline__ int swz(int bid, int chunk) { return (bid & 7) * chunk + (bid >> 3); }

// ---------------- fused init: blocks 0..63 = CSR build; 64..103 = weight prep ----------------
__global__ __launch_bounds__(1024) void k_init(const int* __restrict__ ei,
        int* __restrict__ offs, int* __restrict__ adj, float* __restrict__ dinv,
        const float* __restrict__ wres, const float* __restrict__ gw,
        const float* __restrict__ wfc, unsigned short* __restrict__ Wt) {
    int t = threadIdx.x;
    if (blockIdx.x >= G) {
        // ---- weight prep: fp32 [k][c] -> bf16 Wt[c][k], k-chunk XOR-swizzled ----
        if (t >= 256) return;
        int pb = blockIdx.x - G;           // 0..39
        int m = pb >> 3;
        int tid = (pb & 7) * 256 + t;      // 0..2047
        const float* src = (m == 0) ? wres : (m < 4 ? gw + (size_t)(m-1)*16384 : wfc);
        int c = tid >> 4, q = tid & 15;
        float v[8];
        #pragma unroll
        for (int j = 0; j < 8; ++j) v[j] = src[(q*8 + j)*128 + c];
        uint4 p;
        p.x = pack2(v[0], v[1]); p.y = pack2(v[2], v[3]);
        p.z = pack2(v[4], v[5]); p.w = pack2(v[6], v[7]);
        *reinterpret_cast<uint4*>(Wt + (size_t)m*16384 + c*128 + ((q ^ (c & 7)) << 3)) = p;
        return;
    }
    // ---- CSR build: count + scan + fill, 1 block/graph ----
    int g = blockIdx.x;
    __shared__ int scnt[2048];
    __shared__ int swave[16];
    scnt[t] = 0; scnt[t + 1024] = 0;
    __syncthreads();
    const int* srcp = ei + (size_t)g*2*E;
    const int* dstp = srcp + E;
    for (int e = t; e < E; e += 1024) atomicAdd(&scnt[dstp[e]], 1);
    __syncthreads();
    int a = scnt[2*t], b = scnt[2*t + 1];
    int s = a + b;
    int lane = t & 63, wid = t >> 6;
    #pragma unroll
    for (int d = 1; d < 64; d <<= 1) { int v = __shfl_up(s, d); if (lane >= d) s += v; }
    if (lane == 63) swave[wid] = s;
    __syncthreads();
    if (t < 16) {
        int v = swave[t];
        #pragma unroll
        for (int d = 1; d < 16; d <<= 1) { int u = __shfl_up(v, d); if (t >= d) v += u; }
        swave[t] = v;
    }
    __syncthreads();
    int woff = (wid == 0) ? 0 : swave[wid - 1];
    int e0 = woff + s - (a + b);
    int e1 = e0 + a;
    offs[g*(N+1) + 2*t]     = e0;
    offs[g*(N+1) + 2*t + 1] = e1;
    if (t == 0) offs[g*(N+1) + N] = E;
    dinv[(g<<11) + 2*t]     = rsqrtf((float)(a + 1));
    dinv[(g<<11) + 2*t + 1] = rsqrtf((float)(b + 1));
    scnt[2*t] = e0; scnt[2*t + 1] = e1;
    __syncthreads();
    for (int e = t; e < E; e += 1024) {
        int dst = dstp[e];
        int pos = atomicAdd(&scnt[dst], 1);
        adj[(size_t)g*E + pos] = srcp[e];
    }
}

// ---------------- twin gather-GEMM: X0 read once, two outputs ----------------
// X1 = relu(X0 @ W0 + bres);  Hb = (X0 @ W1) * dinv[row]
__global__ __launch_bounds__(256) void k_gemm_g2(const int* __restrict__ fidx,
        const float* __restrict__ tab, const unsigned short* __restrict__ Wt,
        const float* __restrict__ bres, const float* __restrict__ dinv,
        unsigned short* __restrict__ X1, unsigned short* __restrict__ Hb) {
    __shared__ unsigned short sW[2*16384];   // 64 KB: W0 | W1, pre-swizzled
    const int t = threadIdx.x;
    {
        const float4* s = reinterpret_cast<const float4*>(Wt);
        float4* d = reinterpret_cast<float4*>(sW);
        #pragma unroll
        for (int i = 0; i < 16; ++i) d[i*256 + t] = s[i*256 + t];
    }
    __syncthreads();

    const int lane = t & 63, w = t >> 6;
    const int wrow = (w & 1) << 6;
    const int wcol = (w >> 1) << 6;
    const size_t row0 = (size_t)swz(blockIdx.x, GN/128/8) * 128;
    const int l15 = lane & 15, l4 = lane >> 4;

    size_t rbase[4];
    const float* rowp[4];
    #pragma unroll
    for (int f2 = 0; f2 < 4; ++f2) {
        rbase[f2] = row0 + wrow + f2*16 + l15;
        rowp[f2] = tab + (size_t)fidx[rbase[f2]] * 128;
    }

    f32x4 acc0[4][4], acc1[4][4];
    #pragma unroll
    for (int i = 0; i < 4; ++i)
        #pragma unroll
        for (int j = 0; j < 4; ++j) {
            acc0[i][j] = (f32x4){0.f, 0.f, 0.f, 0.f};
            acc1[i][j] = (f32x4){0.f, 0.f, 0.f, 0.f};
        }

    #pragma unroll
    for (int kk = 0; kk < 4; ++kk) {
        bf16x8 xf[4];
        #pragma unroll
        for (int f2 = 0; f2 < 4; ++f2) {
            int col = (kk << 5) + (l4 << 3);
            float4 u = ld4(rowp[f2] + col);
            float4 v = ld4(rowp[f2] + col + 4);
            bf16x8 r;
            r[0] = (short)f2bf(u.x); r[1] = (short)f2bf(u.y);
            r[2] = (short)f2bf(u.z); r[3] = (short)f2bf(u.w);
            r[4] = (short)f2bf(v.x); r[5] = (short)f2bf(v.y);
            r[6] = (short)f2bf(v.z); r[7] = (short)f2bf(v.w);
            xf[f2] = r;
        }
        #pragma unroll
        for (int f = 0; f < 4; ++f) {
            int c = wcol + f*16 + l15;
            int off = c*128 + (((kk*4 + l4) ^ (c & 7)) << 3);
            bf16x8 wf0 = *reinterpret_cast<const bf16x8*>(&sW[off]);
            bf16x8 wf1 = *reinterpret_cast<const bf16x8*>(&sW[16384 + off]);
            #pragma unroll
            for (int f2 = 0; f2 < 4; ++f2) {
                acc0[f2][f] = __builtin_amdgcn_mfma_f32_16x16x32_bf16(wf0, xf[f2], acc0[f2][f], 0, 0, 0);
                acc1[f2][f] = __builtin_amdgcn_mfma_f32_16x16x32_bf16(wf1, xf[f2], acc1[f2][f], 0, 0, 0);
            }
        }
    }

    float dv[4];
    #pragma unroll
    for (int f2 = 0; f2 < 4; ++f2) dv[f2] = dinv[rbase[f2]];

    #pragma unroll
    for (int f = 0; f < 4; ++f) {
        int colb = wcol + f*16 + (l4 << 2);
        float4 bs = ld4(bres + colb);
        #pragma unroll
        for (int f2 = 0; f2 < 4; ++f2) {
            f32x4 v0 = acc0[f2][f];
            uint2 p0;
            p0.x = pack2(fmaxf(v0[0] + bs.x, 0.f), fmaxf(v0[1] + bs.y, 0.f));
            p0.y = pack2(fmaxf(v0[2] + bs.z, 0.f), fmaxf(v0[3] + bs.w, 0.f));
            *reinterpret_cast<uint2*>(X1 + (rbase[f2] << 7) + colb) = p0;
            f32x4 v1 = acc1[f2][f];
            float d = dv[f2];
            uint2 p1;
            p1.x = pack2(v1[0]*d, v1[1]*d);
            p1.y = pack2(v1[2]*d, v1[3]*d);
            *reinterpret_cast<uint2*>(Hb + (rbase[f2] << 7) + colb) = p1;
        }
    }
}

// ---------------- MFMA GEMM: 128-row tiles, XCD-swizzled ----------------
// MODE 1: C = (A@W) * dinv[row]
// MODE 2: colsum(relu((A+A2)@W + bias)) -> atomicAdd tgt  (no C write)
template<int MODE>
__global__ __launch_bounds__(256) void k_gemm(const unsigned short* __restrict__ A,
        const unsigned short* __restrict__ A2, const unsigned short* __restrict__ Wt,
        const float* __restrict__ bias, const float* __restrict__ dinv,
        unsigned short* __restrict__ C, float* __restrict__ tgt) {
    __shared__ unsigned short sW[16384];   // 32 KB, pre-swizzled
    const int t = threadIdx.x;
    {
        const float4* s = reinterpret_cast<const float4*>(Wt);
        float4* d = reinterpret_cast<float4*>(sW);
        #pragma unroll
        for (int i = 0; i < 8; ++i) d[i*256 + t] = s[i*256 + t];
    }
    __syncthreads();

    const int lane = t & 63, w = t >> 6;
    const int wrow = (w & 1) << 6;
    const int wcol = (w >> 1) << 6;
    const size_t row0 = (size_t)swz(blockIdx.x, GN/128/8) * 128;
    const int l15 = lane & 15, l4 = lane >> 4;

    size_t rbase[4];
    #pragma unroll
    for (int f2 = 0; f2 < 4; ++f2) rbase[f2] = row0 + wrow + f2*16 + l15;

    f32x4 acc[4][4];
    #pragma unroll
    for (int i = 0; i < 4; ++i)
        #pragma unroll
        for (int j = 0; j < 4; ++j) acc[i][j] = (f32x4){0.f, 0.f, 0.f, 0.f};

    #pragma unroll
    for (int kk = 0; kk < 4; ++kk) {
        bf16x8 xf[4];
        #pragma unroll
        for (int f2 = 0; f2 < 4; ++f2) {
            const unsigned short* ap = A + (rbase[f2] << 7) + (kk << 5) + (l4 << 3);
            if (MODE == 2) {
                bf16x8 x = *reinterpret_cast<const bf16x8*>(ap);
                bf16x8 y = *reinterpret_cast<const bf16x8*>(A2 + (rbase[f2] << 7) + (kk << 5) + (l4 << 3));
                bf16x8 r;
                #pragma unroll
                for (int j = 0; j < 8; ++j) r[j] = (short)f2bf(bfs(x[j]) + bfs(y[j]));
                xf[f2] = r;
            } else {
                xf[f2] = *reinterpret_cast<const bf16x8*>(ap);
            }
        }
        #pragma unroll
        for (int f = 0; f < 4; ++f) {
            int c = wcol + f*16 + l15;
            int off = c*128 + (((kk*4 + l4) ^ (c & 7)) << 3);
            bf16x8 wf = *reinterpret_cast<const bf16x8*>(&sW[off]);
            #pragma unroll
            for (int f2 = 0; f2 < 4; ++f2)
                acc[f2][f] = __builtin_amdgcn_mfma_f32_16x16x32_bf16(wf, xf[f2], acc[f2][f], 0, 0, 0);
        }
    }

    if (MODE == 2) {
        float cs[4][4];
        #pragma unroll
        for (int f = 0; f < 4; ++f) {
            int colb = wcol + f*16 + (l4 << 2);
            float4 bs = ld4(bias + colb);
            #pragma unroll
            for (int j = 0; j < 4; ++j) cs[f][j] = 0.f;
            #pragma unroll
            for (int f2 = 0; f2 < 4; ++f2) {
                cs[f][0] += fmaxf(acc[f2][f][0] + bs.x, 0.f);
                cs[f][1] += fmaxf(acc[f2][f][1] + bs.y, 0.f);
                cs[f][2] += fmaxf(acc[f2][f][2] + bs.z, 0.f);
                cs[f][3] += fmaxf(acc[f2][f][3] + bs.w, 0.f);
            }
        }
        #pragma unroll
        for (int d = 1; d < 16; d <<= 1)
            #pragma unroll
            for (int f = 0; f < 4; ++f)
                #pragma unroll
                for (int j = 0; j < 4; ++j)
                    cs[f][j] += __shfl_xor(cs[f][j], d);
        if (l15 == 0) {
            int g = (int)(row0 >> 11);
            #pragma unroll
            for (int f = 0; f < 4; ++f)
                #pragma unroll
                for (int j = 0; j < 4; ++j)
                    atomicAdd(&tgt[g*128 + wcol + f*16 + (l4 << 2) + j], cs[f][j]);
        }
        return;
    }

    float dv[4];
    #pragma unroll
    for (int f2 = 0; f2 < 4; ++f2) dv[f2] = dinv[rbase[f2]];
    #pragma unroll
    for (int f = 0; f < 4; ++f) {
        int colb = wcol + f*16 + (l4 << 2);
        #pragma unroll
        for (int f2 = 0; f2 < 4; ++f2) {
            f32x4 v = acc[f2][f];
            float d = dv[f2];
            uint2 p; p.x = pack2(v[0]*d, v[1]*d); p.y = pack2(v[2]*d, v[3]*d);
            *reinterpret_cast<uint2*>(C + (rbase[f2] << 7) + colb) = p;
        }
    }
}

// ---------------- aggregation (pull via CSR, bf16 in/out), XCD-swizzled ----------------
__global__ __launch_bounds__(256) void k_agg(const unsigned short* __restrict__ h,
        const int* __restrict__ adj, const int* __restrict__ offs,
        const float* __restrict__ dinv, const float* __restrict__ bias,
        unsigned short* __restrict__ out) {
    int bid = swz(blockIdx.x, GN/4/8);
    int wid = bid * 4 + (threadIdx.x >> 6);   // one wave per node
    int lane = threadIdx.x & 63;
    int g = wid >> 11, n = wid & (N-1);
    const unsigned short* hg = h + ((size_t)(g << 11) << 7);
    int st = offs[g*(N+1) + n];
    int en = offs[g*(N+1) + n + 1];
    const int* al = adj + (size_t)g*E;
    const int c2 = lane << 1;
    unsigned us = *reinterpret_cast<const unsigned*>(hg + ((size_t)n << 7) + c2);
    float ax = bflo(us), ay = bfhi(us);   // self-loop term
    int e = st;
    for (; e + 4 <= en; e += 4) {
        int s0 = al[e], s1 = al[e+1], s2 = al[e+2], s3 = al[e+3];
        unsigned u0 = *reinterpret_cast<const unsigned*>(hg + ((size_t)s0 << 7) + c2);
        unsigned u1 = *reinterpret_cast<const unsigned*>(hg + ((size_t)s1 << 7) + c2);
        unsigned u2 = *reinterpret_cast<const unsigned*>(hg + ((size_t)s2 << 7) + c2);
        unsigned u3 = *reinterpret_cast<const unsigned*>(hg + ((size_t)s3 << 7) + c2);
        ax += (bflo(u0) + bflo(u1)) + (bflo(u2) + bflo(u3));
        ay += (bfhi(u0) + bfhi(u1)) + (bfhi(u2) + bfhi(u3));
    }
    for (; e < en; ++e) {
        unsigned u = *reinterpret_cast<const unsigned*>(hg + ((size_t)al[e] << 7) + c2);
        ax += bflo(u); ay += bfhi(u);
    }
    float d = dinv[wid];
    unsigned pv = pack2(fmaxf(ax*d + bias[c2], 0.f), fmaxf(ay*d + bias[c2+1], 0.f));
    *reinterpret_cast<unsigned*>(out + ((size_t)wid << 7) + c2) = pv;
}

// ---------------- logits + log_softmax: one wave per graph ----------------
__global__ __launch_bounds__(64) void k_final(const float* __restrict__ tgt,
        const float* __restrict__ lw, const float* __restrict__ lb, float* __restrict__ outp) {
    int g = blockIdx.x, lane = threadIdx.x;
    float l0 = 0.f, l1 = 0.f;
    #pragma unroll
    for (int c = lane; c < 128; c += 64) {
        float v = tgt[g*128 + c] * (1.0f/2048.0f);
        l0 += v * lw[c*2];
        l1 += v * lw[c*2 + 1];
    }
    #pragma unroll
    for (int d = 32; d; d >>= 1) { l0 += __shfl_xor(l0, d); l1 += __shfl_xor(l1, d); }
    if (lane == 0) {
        l0 += lb[0]; l1 += lb[1];
        float m = fmaxf(l0, l1);
        float lse = m + logf(expf(l0 - m) + expf(l1 - m));
        outp[g*2]         = l0 - lse;
        outp[g*2 + 1]     = l1 - lse;
        outp[G*2 + g*2]     = l0;
        outp[G*2 + g*2 + 1] = l1;
    }
}

extern "C" void kernel_launch(void* const* d_in, const int* in_sizes, int n_in,
                              void* d_out, int out_size, void* d_ws, size_t ws_size,
                              hipStream_t stream) {
    const float* all_features = (const float*)d_in[0];
    const int*   fidx = (const int*)d_in[1];
    const int*   ei   = (const int*)d_in[2];
    // d_in[3] = action (always 2 -> 3 GCN layers)
    const float* wres = (const float*)d_in[4];
    const float* bres = (const float*)d_in[5];
    const float* gw   = (const float*)d_in[6];
    const float* gb   = (const float*)d_in[7];
    const float* wfc  = (const float*)d_in[8];
    const float* bfc  = (const float*)d_in[9];
    const float* lw   = (const float*)d_in[10];
    const float* lb   = (const float*)d_in[11];
    float* out = (float*)d_out;

    char* ws = (char*)d_ws;
    size_t o = 0;
    auto alloc = [&](size_t bytes) { char* p = ws + o; o += (bytes + 255) & ~(size_t)255; return p; };
    unsigned short* X  = (unsigned short*)alloc((size_t)GN*128*2);
    unsigned short* Hb = (unsigned short*)alloc((size_t)GN*128*2);
    unsigned short* X1 = (unsigned short*)alloc((size_t)GN*128*2);
    unsigned short* Wt = (unsigned short*)alloc((size_t)5*16384*2);
    int*   adj  = (int*)alloc((size_t)G*E*4);
    int*   offs = (int*)alloc((size_t)G*(N+1)*4);
    float* dinv = (float*)alloc((size_t)GN*4);
    float* tgt  = (float*)alloc((size_t)G*128*4);

    hipMemsetAsync(tgt, 0, (size_t)G*128*4, stream);

    // CSR build + weight prep (one launch)
    k_init<<<G + 40, 1024, 0, stream>>>(ei, offs, adj, dinv, wres, gw, wfc, Wt);

    // twin gather-GEMM: X1 = relu(X0@Wres+bres), Hb = (X0@Wgcn0)*dinv — X0 read once
    k_gemm_g2<<<GN/128, 256, 0, stream>>>(fidx, all_features, Wt, bres, dinv, X1, Hb);

    // layer 0 aggregation, then layers 1..2
    k_agg<<<GN/4, 256, 0, stream>>>(Hb, adj, offs, dinv, gb, X);
    for (int l = 1; l < 3; ++l) {
        k_gemm<1><<<GN/128, 256, 0, stream>>>(X, nullptr, Wt + (size_t)(1+l)*16384, nullptr, dinv, Hb, nullptr);
        k_agg<<<GN/4, 256, 0, stream>>>(Hb, adj, offs, dinv, gb + (size_t)l*128, X);
    }

    // fc1 + mean fused: atomicAdd col-sums of relu((X+X1)@Wfc+bfc) into tgt
    k_gemm<2><<<GN/128, 256, 0, stream>>>(X, X1, Wt + (size_t)4*16384, bfc, nullptr, nullptr, tgt);

    k_final<<<G, 64, 0, stream>>>(tgt, lw, lb, out);
}